// Round 2
// baseline (1466.261 us; speedup 1.0000x reference)
//
#include <hip/hip_runtime.h>
#include <hip/hip_bf16.h>
#include <hip/hip_fp16.h>

// ---------------------------------------------------------------------------
// Fused persistent-kernel MLP: 10 x (Linear -> BatchNorm(train) -> tanh) +
// Linear -> sigmoid, B = 2^20 rows.
//
// R2 change vs R1: R1 spilled (VGPR=64, 84MB scratch writes, 215MB scratch
// reads -> 1.3ms). Fix: post-tanh activations are packed f16 pairs (__half2)
// so peak live state (acc fp32 + packed buf) fits the 128-VGPR cap from
// __launch_bounds__(256,4). Pre-BN h stays fp32 for exact batch stats.
// ---------------------------------------------------------------------------

#define NBLK 1024
#define NTHR 256
#define RPT  4
#define BATCHN 1048576
#define NREP 32        // LDS stat replicas (stride 49 odd -> bank bijection)
#define SSTR 49
#define GSLOTS 8       // global stat/barrier contention splitting
#define GSTR 48        // per-slot float stride: [0..23]=sum, [24..47]=sumsq

static_assert(NBLK * NTHR * RPT == BATCHN, "row coverage");

static constexpr int D_[12] = {64, 4, 20, 10, 10, 10, 10, 10, 5, 5, 5, 1};

static constexpr int pad4c(int x) { return (x + 3) & ~3; }
static constexpr int woffc(int l) {
    int o = 0;
    for (int k = 0; k < l; ++k) o += D_[k + 1] * pad4c(D_[k]);
    return o;
}
static constexpr int boffc(int l) {
    int o = 0;
    for (int k = 0; k < l; ++k) o += D_[k + 1];
    return o;
}
static constexpr int WTOT = woffc(11);  // padded weights (floats)
static constexpr int BTOT = boffc(11);  // 90 biases
static constexpr int GTOT = boffc(10);  // 89 BN gammas/betas

struct Params {
    const float* x;
    const float* W[11];
    const float* b[11];
    const float* g[10];
    const float* bt[10];
    float* out;
    float* gstats;   // [10][GSLOTS][GSTR]
    unsigned* bar;   // [10][GSLOTS]
};

__device__ __forceinline__ float fast_tanh(float x) {
    // tanh(x) = 1 - 2/(exp2(2*log2e*x)+1); exp2f -> v_exp_f32
    float e = exp2f(x * 2.8853900817779268f);
    return 1.0f - __fdividef(2.0f, e + 1.0f);
}

// ---- staging helpers -------------------------------------------------------
template <int L>
__device__ __forceinline__ void stageW(const Params& p, float* lW, int tid) {
    constexpr int DIN = D_[L], DOUT = D_[L + 1], PD = pad4c(DIN), WO = woffc(L);
    for (int i = tid; i < DOUT * DIN; i += NTHR) {
        int o = i / DIN;          // compile-time divisor -> mul/shift
        int c = i - o * DIN;
        lW[WO + o * PD + c] = p.W[L][i];
    }
}

template <int L>
__device__ __forceinline__ void stageB(const Params& p, float* lB, float* lG,
                                       float* lT, int tid) {
    constexpr int DOUT = D_[L + 1], BO = boffc(L);
    if (tid < DOUT) {
        lB[BO + tid] = p.b[L][tid];
        if (L < 10) {
            lG[BO + tid] = p.g[L][tid];
            lT[BO + tid] = p.bt[L][tid];
        }
    }
}

// ---- BN(batch stats) + tanh -> packed f16 pairs, device-wide barrier -------
template <int L, int DOUT>
__device__ __forceinline__ void bn_stats_tanh(const Params& p,
                                              float (&acc)[RPT][DOUT],
                                              __half2 (&buf)[RPT][10],
                                              const float* lG, const float* lT,
                                              float* bsum, float* lsc, float* lsh,
                                              int tid, int bslot) {
    // guard reuse of bsum/lsc/lsh from previous layer
    __syncthreads();
    for (int i = tid; i < NREP * SSTR; i += NTHR) bsum[i] = 0.0f;
    __syncthreads();

    // per-thread 4-row sums -> replicated LDS accumulators (conflict-free)
    const int rep = (tid & 31) * SSTR;
#pragma unroll
    for (int d = 0; d < DOUT; ++d) {
        float a0 = acc[0][d], a1 = acc[1][d], a2 = acc[2][d], a3 = acc[3][d];
        float s = (a0 + a1) + (a2 + a3);
        float s2 = fmaf(a0, a0, fmaf(a1, a1, fmaf(a2, a2, a3 * a3)));
        atomicAdd(&bsum[rep + d], s);
        atomicAdd(&bsum[rep + 24 + d], s2);
    }
    __syncthreads();

    // fold replicas, one global atomic per block per feature (8-way slots)
    if (tid < 2 * DOUT) {
        const int idx = (tid < DOUT) ? tid : (24 + (tid - DOUT));
        float v = 0.0f;
        for (int r = 0; r < NREP; ++r) v += bsum[r * SSTR + idx];
        atomicAdd(&p.gstats[(L * GSLOTS + bslot) * GSTR + idx], v);
    }
    __syncthreads();

    // device-wide barrier: one arrival per block, 8-way split counters
    if (tid == 0) {
        __hip_atomic_fetch_add(&p.bar[L * GSLOTS + bslot], 1u,
                               __ATOMIC_RELEASE, __HIP_MEMORY_SCOPE_AGENT);
        unsigned tot = 0;
        do {
            tot = 0;
            for (int q = 0; q < GSLOTS; ++q)
                tot += __hip_atomic_load(&p.bar[L * GSLOTS + q],
                                         __ATOMIC_RELAXED, __HIP_MEMORY_SCOPE_AGENT);
            if (tot < NBLK) __builtin_amdgcn_s_sleep(2);
        } while (tot < NBLK);
        // acquire fence so subsequent gstats reads observe all releases
        (void)__hip_atomic_load(&p.bar[L * GSLOTS], __ATOMIC_ACQUIRE,
                                __HIP_MEMORY_SCOPE_AGENT);
    }
    __syncthreads();

    // every block computes scale/shift from global sums
    if (tid < DOUT) {
        float s = 0.0f, s2 = 0.0f;
        for (int q = 0; q < GSLOTS; ++q) {
            s += __hip_atomic_load(&p.gstats[(L * GSLOTS + q) * GSTR + tid],
                                   __ATOMIC_RELAXED, __HIP_MEMORY_SCOPE_AGENT);
            s2 += __hip_atomic_load(&p.gstats[(L * GSLOTS + q) * GSTR + 24 + tid],
                                    __ATOMIC_RELAXED, __HIP_MEMORY_SCOPE_AGENT);
        }
        constexpr float inv = 1.0f / (float)BATCHN;
        float m = s * inv;
        float var = fmaxf(s2 * inv - m * m, 0.0f);
        float scv = lG[boffc(L) + tid] * rsqrtf(var + 1e-5f);
        lsc[tid] = scv;
        lsh[tid] = lT[boffc(L) + tid] - m * scv;
    }
    __syncthreads();

    // normalize + tanh + pack to f16 pairs (tanh out in [-1,1]: f16 is safe)
    constexpr int OP = (DOUT + 1) / 2;
#pragma unroll
    for (int j = 0; j < RPT; ++j) {
#pragma unroll
        for (int q = 0; q < OP; ++q) {
            const int d0 = 2 * q, d1 = 2 * q + 1;
            float t0 = fast_tanh(fmaf(acc[j][d0], lsc[d0], lsh[d0]));
            float t1 = (d1 < DOUT)
                           ? fast_tanh(fmaf(acc[j][d1], lsc[d1], lsh[d1]))
                           : 0.0f;
            buf[j][q] = __floats2half2_rn(t0, t1);
        }
    }
}

// ---- generic hidden layer (L = 1..9): Linear from packed buf -> BN -> tanh -
template <int L>
__device__ __forceinline__ void layer_bn(const Params& p, const float* lW,
                                         const float* lB, const float* lG,
                                         const float* lT, float* bsum,
                                         float* lsc, float* lsh,
                                         __half2 (&buf)[RPT][10], int tid, int bslot) {
    constexpr int DIN = D_[L], DOUT = D_[L + 1];
    constexpr int NP = (DIN + 1) / 2;   // input pairs (pad half is 0)
    constexpr int PD = pad4c(DIN), WO = woffc(L), BO = boffc(L);
    float acc[RPT][DOUT];
#pragma unroll
    for (int j = 0; j < RPT; ++j)
#pragma unroll
        for (int o = 0; o < DOUT; ++o) acc[j][o] = lB[BO + o];

#pragma unroll
    for (int cp = 0; cp < NP; ++cp) {
        float x0[RPT], x1[RPT];
#pragma unroll
        for (int j = 0; j < RPT; ++j) {
            const __half2 v = buf[j][cp];
            x0[j] = __low2float(v);
            x1[j] = __high2float(v);
        }
#pragma unroll
        for (int o = 0; o < DOUT; ++o) {
            const float2 w = *(const float2*)&lW[WO + o * PD + 2 * cp];
#pragma unroll
            for (int j = 0; j < RPT; ++j)
                acc[j][o] = fmaf(w.x, x0[j], fmaf(w.y, x1[j], acc[j][o]));
        }
    }
    bn_stats_tanh<L, DOUT>(p, acc, buf, lG, lT, bsum, lsc, lsh, tid, bslot);
}

// ---------------------------------------------------------------------------
__global__ void __launch_bounds__(NTHR, 4) mlp_fused(Params p) {
    __shared__ __align__(16) float lW[WTOT];
    __shared__ float lB[BTOT];
    __shared__ float lG[GTOT];
    __shared__ float lT[GTOT];
    __shared__ float bsum[NREP * SSTR];
    __shared__ float lsc[20], lsh[20];

    const int tid = threadIdx.x;
    const int bslot = blockIdx.x & (GSLOTS - 1);

    // stage weights to LDS (zero first -> padded columns are 0)
    for (int i = tid; i < WTOT; i += NTHR) lW[i] = 0.0f;
    __syncthreads();
    stageW<0>(p, lW, tid);  stageW<1>(p, lW, tid);  stageW<2>(p, lW, tid);
    stageW<3>(p, lW, tid);  stageW<4>(p, lW, tid);  stageW<5>(p, lW, tid);
    stageW<6>(p, lW, tid);  stageW<7>(p, lW, tid);  stageW<8>(p, lW, tid);
    stageW<9>(p, lW, tid);  stageW<10>(p, lW, tid);
    stageB<0>(p, lB, lG, lT, tid);  stageB<1>(p, lB, lG, lT, tid);
    stageB<2>(p, lB, lG, lT, tid);  stageB<3>(p, lB, lG, lT, tid);
    stageB<4>(p, lB, lG, lT, tid);  stageB<5>(p, lB, lG, lT, tid);
    stageB<6>(p, lB, lG, lT, tid);  stageB<7>(p, lB, lG, lT, tid);
    stageB<8>(p, lB, lG, lT, tid);  stageB<9>(p, lB, lG, lT, tid);
    stageB<10>(p, lB, lG, lT, tid);
    __syncthreads();

    // rows handled by this thread: rowbase + j*NTHR  (coalesced across lanes)
    const int rowbase = blockIdx.x * (NTHR * RPT) + tid;

    __half2 buf[RPT][10];   // packed post-tanh activations (<=20 wide)

    // ---- layer 0: x(64) -> 4, streamed from HBM ----
    {
        float acc[RPT][4];
#pragma unroll
        for (int j = 0; j < RPT; ++j)
#pragma unroll
            for (int o = 0; o < 4; ++o) acc[j][o] = lB[boffc(0) + o];
#pragma unroll
        for (int c = 0; c < 16; ++c) {
            const float4 w0 = *(const float4*)&lW[woffc(0) + 0 * 64 + c * 4];
            const float4 w1 = *(const float4*)&lW[woffc(0) + 1 * 64 + c * 4];
            const float4 w2 = *(const float4*)&lW[woffc(0) + 2 * 64 + c * 4];
            const float4 w3 = *(const float4*)&lW[woffc(0) + 3 * 64 + c * 4];
#pragma unroll
            for (int j = 0; j < RPT; ++j) {
                const float4 xv = *(const float4*)(p.x + (size_t)(rowbase + j * NTHR) * 64 + c * 4);
                acc[j][0] = fmaf(w0.x, xv.x, fmaf(w0.y, xv.y, fmaf(w0.z, xv.z, fmaf(w0.w, xv.w, acc[j][0]))));
                acc[j][1] = fmaf(w1.x, xv.x, fmaf(w1.y, xv.y, fmaf(w1.z, xv.z, fmaf(w1.w, xv.w, acc[j][1]))));
                acc[j][2] = fmaf(w2.x, xv.x, fmaf(w2.y, xv.y, fmaf(w2.z, xv.z, fmaf(w2.w, xv.w, acc[j][2]))));
                acc[j][3] = fmaf(w3.x, xv.x, fmaf(w3.y, xv.y, fmaf(w3.z, xv.z, fmaf(w3.w, xv.w, acc[j][3]))));
            }
        }
        bn_stats_tanh<0, 4>(p, acc, buf, lG, lT, bsum, lsc, lsh, tid, bslot);
    }

    // ---- layers 1..9 ----
    layer_bn<1>(p, lW, lB, lG, lT, bsum, lsc, lsh, buf, tid, bslot);
    layer_bn<2>(p, lW, lB, lG, lT, bsum, lsc, lsh, buf, tid, bslot);
    layer_bn<3>(p, lW, lB, lG, lT, bsum, lsc, lsh, buf, tid, bslot);
    layer_bn<4>(p, lW, lB, lG, lT, bsum, lsc, lsh, buf, tid, bslot);
    layer_bn<5>(p, lW, lB, lG, lT, bsum, lsc, lsh, buf, tid, bslot);
    layer_bn<6>(p, lW, lB, lG, lT, bsum, lsc, lsh, buf, tid, bslot);
    layer_bn<7>(p, lW, lB, lG, lT, bsum, lsc, lsh, buf, tid, bslot);
    layer_bn<8>(p, lW, lB, lG, lT, bsum, lsc, lsh, buf, tid, bslot);
    layer_bn<9>(p, lW, lB, lG, lT, bsum, lsc, lsh, buf, tid, bslot);

    // ---- layer 10: 5 -> 1, sigmoid, store ----
    {
        constexpr int WO = woffc(10), BO = boffc(10);
#pragma unroll
        for (int j = 0; j < RPT; ++j) {
            float a = lB[BO];
#pragma unroll
            for (int cp = 0; cp < 3; ++cp) {   // 3 pairs; pair 2 high half = 0
                const float2 w = *(const float2*)&lW[WO + 2 * cp];
                const __half2 v = buf[j][cp];
                a = fmaf(w.x, __low2float(v), fmaf(w.y, __high2float(v), a));
            }
            float e = exp2f(a * -1.4426950408889634f);
            p.out[rowbase + j * NTHR] = __fdividef(1.0f, 1.0f + e);
        }
    }
}

// zero the stats + barrier region each call (ws is NOT re-poisoned between
// graph replays, so this must run every launch)
__global__ void init_ws(float* gstats, unsigned* bar) {
    int i = threadIdx.x + blockIdx.x * blockDim.x;
    if (i < 10 * GSLOTS * GSTR) gstats[i] = 0.0f;
    if (i < 10 * GSLOTS) bar[i] = 0u;
}

extern "C" void kernel_launch(void* const* d_in, const int* in_sizes, int n_in,
                              void* d_out, int out_size, void* d_ws, size_t ws_size,
                              hipStream_t stream) {
    Params p;
    p.x = (const float*)d_in[0];
    int k = 1;
    for (int l = 0; l < 11; ++l) {
        p.W[l] = (const float*)d_in[k++];
        p.b[l] = (const float*)d_in[k++];
        if (l < 10) {
            p.g[l] = (const float*)d_in[k++];
            p.bt[l] = (const float*)d_in[k++];
        }
    }
    p.out = (float*)d_out;
    p.gstats = (float*)d_ws;
    p.bar = (unsigned*)((char*)d_ws + (size_t)(10 * GSLOTS * GSTR) * sizeof(float));

    init_ws<<<dim3((10 * GSLOTS * GSTR + 255) / 256), dim3(256), 0, stream>>>(p.gstats, p.bar);
    mlp_fused<<<dim3(NBLK), dim3(NTHR), 0, stream>>>(p);
}

// Round 3
// 1405.406 us; speedup vs baseline: 1.0433x; 1.0433x over previous
//
#include <hip/hip_runtime.h>
#include <hip/hip_fp16.h>

// ---------------------------------------------------------------------------
// Fused persistent-kernel MLP: 10 x (Linear -> BatchNorm(train) -> tanh) +
// Linear -> sigmoid, B = 2^20 rows.
//
// R3 vs R2: R2 still spilled (VGPR=64, ~260MB scratch traffic). Root causes:
//  (a) fp32 acc[4][20] live across the whole layer -> peak live ~160 regs;
//  (b) allocator budgeted 64 VGPR (8 waves/EU) despite launch_bounds.
// Fix: (1) compute output features in PAIRS (8 live f32 accs), accumulate
// exact f32 stats immediately, store pre-BN h as packed f16 -> peak live
// ~100 regs; stats stay f32-exact (computed before the f16 round).
// (2) pin budget with amdgpu_waves_per_eu(4,4) -> exactly 128 VGPRs,
// 4 blocks/CU, 1024 blocks co-resident (device barrier safe).
// ---------------------------------------------------------------------------

#define NBLK 1024
#define NTHR 256
#define RPT  4
#define BATCHN 1048576
#define NREP 32        // LDS stat replicas (stride 49 odd -> bank bijection)
#define SSTR 49
#define GSLOTS 8       // global stat/barrier contention splitting
#define GSTR 48        // per-slot float stride: [0..23]=sum, [24..47]=sumsq

static_assert(NBLK * NTHR * RPT == BATCHN, "row coverage");

static constexpr int D_[12] = {64, 4, 20, 10, 10, 10, 10, 10, 5, 5, 5, 1};

static constexpr int np_(int d) { return (d + 1) / 2; }
static constexpr int w2offc(int l) {  // float2 offset of layer l (l>=1) weights
    int o = 0;
    for (int k = 1; k < l; ++k) o += D_[k + 1] * np_(D_[k]);
    return o;
}
static constexpr int boffc(int l) {
    int o = 0;
    for (int k = 0; k < l; ++k) o += D_[k + 1];
    return o;
}
static constexpr int W2TOT = w2offc(11);  // 398 float2
static constexpr int BTOT = boffc(11);    // 90
static constexpr int GTOT = boffc(10);    // 89

struct Params {
    const float* x;
    const float* W[11];
    const float* b[11];
    const float* g[10];
    const float* bt[10];
    float* out;
    float* gstats;   // [10][GSLOTS][GSTR]
    unsigned* bar;   // [10][GSLOTS]
};

__device__ __forceinline__ float fast_tanh(float x) {
    // tanh(x) = 1 - 2/(exp2(2*log2e*x)+1); exp2f -> v_exp_f32
    float e = exp2f(x * 2.8853900817779268f);
    return 1.0f - __fdividef(2.0f, e + 1.0f);
}

// ---- staging ----------------------------------------------------------------
template <int L>
__device__ __forceinline__ void stageW2(const Params& p, float2* lW2, int tid) {
    constexpr int DIN = D_[L], DOUT = D_[L + 1], NP = np_(DIN), WO = w2offc(L);
    for (int i = tid; i < DOUT * NP; i += NTHR) {
        const int o = i / NP, cp = i - o * NP;
        const int c0 = 2 * cp, c1 = c0 + 1;
        const float w0 = p.W[L][o * DIN + c0];
        const float w1 = (c1 < DIN) ? p.W[L][o * DIN + c1] : 0.0f;
        lW2[WO + i] = make_float2(w0, w1);
    }
}

template <int L>
__device__ __forceinline__ void stageB(const Params& p, float* lB, float* lG,
                                       float* lT, int tid) {
    constexpr int DOUT = D_[L + 1], BO = boffc(L);
    if (tid < DOUT) {
        lB[BO + tid] = p.b[L][tid];
        if (L < 10) {
            lG[BO + tid] = p.g[L][tid];
            lT[BO + tid] = p.bt[L][tid];
        }
    }
}

// ---- device-wide barrier (one arrival per block, 8-way split counters) ------
__device__ __forceinline__ void device_barrier(const Params& p, int L, int tid,
                                               int bslot) {
    __syncthreads();   // all block-side global atomics complete before arrival
    if (tid == 0) {
        __hip_atomic_fetch_add(&p.bar[L * GSLOTS + bslot], 1u,
                               __ATOMIC_RELEASE, __HIP_MEMORY_SCOPE_AGENT);
        unsigned tot = 0;
        do {
            tot = 0;
            for (int q = 0; q < GSLOTS; ++q)
                tot += __hip_atomic_load(&p.bar[L * GSLOTS + q],
                                         __ATOMIC_RELAXED, __HIP_MEMORY_SCOPE_AGENT);
            if (tot < NBLK) __builtin_amdgcn_s_sleep(2);
        } while (tot < NBLK);
        (void)__hip_atomic_load(&p.bar[L * GSLOTS], __ATOMIC_ACQUIRE,
                                __HIP_MEMORY_SCOPE_AGENT);
    }
    __syncthreads();
}

// ---- fold replicas -> global stats -> barrier -> scale/shift -> tanh --------
// h holds pre-BN values as packed f16; transformed in place to post-tanh acts.
template <int L, int DOUT>
__device__ __forceinline__ void finish_bn(const Params& p, __half2 (&h)[RPT][10],
                                          const float* lG, const float* lT,
                                          float* bsum, float* lsc, float* lsh,
                                          int tid, int bslot) {
    __syncthreads();   // all LDS stat atomics done
    if (tid < 2 * DOUT) {
        const int idx = (tid < DOUT) ? tid : (24 + (tid - DOUT));
        float v = 0.0f;
        for (int r = 0; r < NREP; ++r) v += bsum[r * SSTR + idx];
        atomicAdd(&p.gstats[(L * GSLOTS + bslot) * GSTR + idx], v);
    }
    device_barrier(p, L, tid, bslot);
    if (tid < DOUT) {
        float s = 0.0f, s2 = 0.0f;
        for (int q = 0; q < GSLOTS; ++q) {
            s += __hip_atomic_load(&p.gstats[(L * GSLOTS + q) * GSTR + tid],
                                   __ATOMIC_RELAXED, __HIP_MEMORY_SCOPE_AGENT);
            s2 += __hip_atomic_load(&p.gstats[(L * GSLOTS + q) * GSTR + 24 + tid],
                                    __ATOMIC_RELAXED, __HIP_MEMORY_SCOPE_AGENT);
        }
        constexpr float inv = 1.0f / (float)BATCHN;
        const float m = s * inv;
        const float var = fmaxf(s2 * inv - m * m, 0.0f);
        const float scv = lG[boffc(L) + tid] * rsqrtf(var + 1e-5f);
        lsc[tid] = scv;
        lsh[tid] = lT[boffc(L) + tid] - m * scv;
    }
    __syncthreads();
#pragma unroll
    for (int j = 0; j < RPT; ++j) {
#pragma unroll
        for (int op = 0; op < (DOUT + 1) / 2; ++op) {
            const int o0 = 2 * op, o1 = o0 + 1;
            const float t0 = fast_tanh(fmaf(__low2float(h[j][op]), lsc[o0], lsh[o0]));
            const float t1 = (o1 < DOUT)
                ? fast_tanh(fmaf(__high2float(h[j][op]), lsc[o1], lsh[o1]))
                : 0.0f;
            h[j][op] = __floats2half2_rn(t0, t1);
        }
    }
}

// ---- hidden layer L=1..9: Linear(ain) -> stats -> h(f16) -> BN+tanh ---------
template <int L>
__device__ __forceinline__ void layer_h(const Params& p, const float2* lW2,
                                        const float* lB, const float* lG,
                                        const float* lT, float* bsum,
                                        float* lsc, float* lsh,
                                        const __half2 (&ain)[RPT][10],
                                        __half2 (&hout)[RPT][10],
                                        int tid, int bslot) {
    constexpr int DIN = D_[L], DOUT = D_[L + 1], NP = np_(DIN);
    constexpr int WO = w2offc(L), BO = boffc(L);
    __syncthreads();   // previous layer's bsum reads + lsc/lsh reads done
    for (int i = tid; i < NREP * SSTR; i += NTHR) bsum[i] = 0.0f;
    __syncthreads();
    const int rep = (tid & 31) * SSTR;

#pragma unroll
    for (int op = 0; op < DOUT / 2; ++op) {
        const int o0 = 2 * op, o1 = o0 + 1;
        float a0[RPT], a1[RPT];
#pragma unroll
        for (int j = 0; j < RPT; ++j) { a0[j] = lB[BO + o0]; a1[j] = lB[BO + o1]; }
#pragma unroll
        for (int cp = 0; cp < NP; ++cp) {
            const float2 w0 = lW2[WO + o0 * NP + cp];
            const float2 w1 = lW2[WO + o1 * NP + cp];
#pragma unroll
            for (int j = 0; j < RPT; ++j) {
                const float x0 = __low2float(ain[j][cp]);
                const float x1 = __high2float(ain[j][cp]);
                a0[j] = fmaf(w0.x, x0, fmaf(w0.y, x1, a0[j]));
                a1[j] = fmaf(w1.x, x0, fmaf(w1.y, x1, a1[j]));
            }
        }
        const float s0 = (a0[0] + a0[1]) + (a0[2] + a0[3]);
        const float q0 = fmaf(a0[0], a0[0], fmaf(a0[1], a0[1], fmaf(a0[2], a0[2], a0[3] * a0[3])));
        const float s1 = (a1[0] + a1[1]) + (a1[2] + a1[3]);
        const float q1 = fmaf(a1[0], a1[0], fmaf(a1[1], a1[1], fmaf(a1[2], a1[2], a1[3] * a1[3])));
        atomicAdd(&bsum[rep + o0], s0);      atomicAdd(&bsum[rep + 24 + o0], q0);
        atomicAdd(&bsum[rep + o1], s1);      atomicAdd(&bsum[rep + 24 + o1], q1);
#pragma unroll
        for (int j = 0; j < RPT; ++j) hout[j][op] = __floats2half2_rn(a0[j], a1[j]);
    }
    if constexpr (DOUT & 1) {
        constexpr int o0 = DOUT - 1;
        float a0[RPT];
#pragma unroll
        for (int j = 0; j < RPT; ++j) a0[j] = lB[BO + o0];
#pragma unroll
        for (int cp = 0; cp < NP; ++cp) {
            const float2 w0 = lW2[WO + o0 * NP + cp];
#pragma unroll
            for (int j = 0; j < RPT; ++j)
                a0[j] = fmaf(w0.x, __low2float(ain[j][cp]),
                        fmaf(w0.y, __high2float(ain[j][cp]), a0[j]));
        }
        const float s0 = (a0[0] + a0[1]) + (a0[2] + a0[3]);
        const float q0 = fmaf(a0[0], a0[0], fmaf(a0[1], a0[1], fmaf(a0[2], a0[2], a0[3] * a0[3])));
        atomicAdd(&bsum[rep + o0], s0);      atomicAdd(&bsum[rep + 24 + o0], q0);
#pragma unroll
        for (int j = 0; j < RPT; ++j) hout[j][DOUT / 2] = __floats2half2_rn(a0[j], 0.0f);
    }
    finish_bn<L, D_[L + 1]>(p, hout, lG, lT, bsum, lsc, lsh, tid, bslot);
}

// ---------------------------------------------------------------------------
__global__ void
__attribute__((amdgpu_flat_work_group_size(NTHR, NTHR), amdgpu_waves_per_eu(4, 4)))
mlp_fused(Params p) {
    __shared__ __align__(16) float lW0[256];     // layer-0 weights f32 [4][64]
    __shared__ __align__(8) float2 lW2[W2TOT];   // layers 1..10, paired f32
    __shared__ float lB[BTOT], lG[GTOT], lT[GTOT];
    __shared__ float bsum[NREP * SSTR];
    __shared__ float lsc[20], lsh[20];

    const int tid = threadIdx.x;
    const int bslot = blockIdx.x & (GSLOTS - 1);

    for (int i = tid; i < 256; i += NTHR) lW0[i] = p.W[0][i];
    stageW2<1>(p, lW2, tid);  stageW2<2>(p, lW2, tid);  stageW2<3>(p, lW2, tid);
    stageW2<4>(p, lW2, tid);  stageW2<5>(p, lW2, tid);  stageW2<6>(p, lW2, tid);
    stageW2<7>(p, lW2, tid);  stageW2<8>(p, lW2, tid);  stageW2<9>(p, lW2, tid);
    stageW2<10>(p, lW2, tid);
    stageB<0>(p, lB, lG, lT, tid);  stageB<1>(p, lB, lG, lT, tid);
    stageB<2>(p, lB, lG, lT, tid);  stageB<3>(p, lB, lG, lT, tid);
    stageB<4>(p, lB, lG, lT, tid);  stageB<5>(p, lB, lG, lT, tid);
    stageB<6>(p, lB, lG, lT, tid);  stageB<7>(p, lB, lG, lT, tid);
    stageB<8>(p, lB, lG, lT, tid);  stageB<9>(p, lB, lG, lT, tid);
    stageB<10>(p, lB, lG, lT, tid);
    __syncthreads();

    const int rowbase = blockIdx.x * (NTHR * RPT) + tid;  // + j*NTHR, coalesced

    __half2 A[RPT][10], B[RPT][10];   // ping-pong packed activations / pre-BN h

    // ---- layer 0: x(64) -> 4, streamed from HBM, f32 accumulate ----
    {
        float acc[RPT][4];
#pragma unroll
        for (int j = 0; j < RPT; ++j)
#pragma unroll
            for (int o = 0; o < 4; ++o) acc[j][o] = lB[boffc(0) + o];
#pragma unroll
        for (int c = 0; c < 16; ++c) {
            const float4 w0 = *(const float4*)&lW0[0 * 64 + c * 4];
            const float4 w1 = *(const float4*)&lW0[1 * 64 + c * 4];
            const float4 w2 = *(const float4*)&lW0[2 * 64 + c * 4];
            const float4 w3 = *(const float4*)&lW0[3 * 64 + c * 4];
#pragma unroll
            for (int j = 0; j < RPT; ++j) {
                const float4 xv = *(const float4*)(p.x + (size_t)(rowbase + j * NTHR) * 64 + c * 4);
                acc[j][0] = fmaf(w0.x, xv.x, fmaf(w0.y, xv.y, fmaf(w0.z, xv.z, fmaf(w0.w, xv.w, acc[j][0]))));
                acc[j][1] = fmaf(w1.x, xv.x, fmaf(w1.y, xv.y, fmaf(w1.z, xv.z, fmaf(w1.w, xv.w, acc[j][1]))));
                acc[j][2] = fmaf(w2.x, xv.x, fmaf(w2.y, xv.y, fmaf(w2.z, xv.z, fmaf(w2.w, xv.w, acc[j][2]))));
                acc[j][3] = fmaf(w3.x, xv.x, fmaf(w3.y, xv.y, fmaf(w3.z, xv.z, fmaf(w3.w, xv.w, acc[j][3]))));
            }
        }
        __syncthreads();
        for (int i = tid; i < NREP * SSTR; i += NTHR) bsum[i] = 0.0f;
        __syncthreads();
        const int rep = (tid & 31) * SSTR;
#pragma unroll
        for (int d = 0; d < 4; ++d) {
            const float s = (acc[0][d] + acc[1][d]) + (acc[2][d] + acc[3][d]);
            const float q = fmaf(acc[0][d], acc[0][d], fmaf(acc[1][d], acc[1][d],
                            fmaf(acc[2][d], acc[2][d], acc[3][d] * acc[3][d])));
            atomicAdd(&bsum[rep + d], s);
            atomicAdd(&bsum[rep + 24 + d], q);
        }
#pragma unroll
        for (int j = 0; j < RPT; ++j) {
            A[j][0] = __floats2half2_rn(acc[j][0], acc[j][1]);
            A[j][1] = __floats2half2_rn(acc[j][2], acc[j][3]);
        }
        finish_bn<0, 4>(p, A, lG, lT, bsum, lsc, lsh, tid, bslot);
    }

    // ---- layers 1..9 (ping-pong A/B) ----
    layer_h<1>(p, lW2, lB, lG, lT, bsum, lsc, lsh, A, B, tid, bslot);
    layer_h<2>(p, lW2, lB, lG, lT, bsum, lsc, lsh, B, A, tid, bslot);
    layer_h<3>(p, lW2, lB, lG, lT, bsum, lsc, lsh, A, B, tid, bslot);
    layer_h<4>(p, lW2, lB, lG, lT, bsum, lsc, lsh, B, A, tid, bslot);
    layer_h<5>(p, lW2, lB, lG, lT, bsum, lsc, lsh, A, B, tid, bslot);
    layer_h<6>(p, lW2, lB, lG, lT, bsum, lsc, lsh, B, A, tid, bslot);
    layer_h<7>(p, lW2, lB, lG, lT, bsum, lsc, lsh, A, B, tid, bslot);
    layer_h<8>(p, lW2, lB, lG, lT, bsum, lsc, lsh, B, A, tid, bslot);
    layer_h<9>(p, lW2, lB, lG, lT, bsum, lsc, lsh, A, B, tid, bslot);

    // ---- layer 10: 5 -> 1, sigmoid, store (reads B; B[j][2].y == 0) ----
    {
        constexpr int WO = w2offc(10), BO = boffc(10);
#pragma unroll
        for (int j = 0; j < RPT; ++j) {
            float a = lB[BO];
#pragma unroll
            for (int cp = 0; cp < 3; ++cp) {
                const float2 w = lW2[WO + cp];
                a = fmaf(w.x, __low2float(B[j][cp]),
                    fmaf(w.y, __high2float(B[j][cp]), a));
            }
            const float e = exp2f(a * -1.4426950408889634f);
            p.out[rowbase + j * NTHR] = __fdividef(1.0f, 1.0f + e);
        }
    }
}

// zero the stats + barrier region each call (ws is NOT re-poisoned between
// graph replays, so this must run every launch)
__global__ void init_ws(float* gstats, unsigned* bar) {
    int i = threadIdx.x + blockIdx.x * blockDim.x;
    if (i < 10 * GSLOTS * GSTR) gstats[i] = 0.0f;
    if (i < 10 * GSLOTS) bar[i] = 0u;
}

extern "C" void kernel_launch(void* const* d_in, const int* in_sizes, int n_in,
                              void* d_out, int out_size, void* d_ws, size_t ws_size,
                              hipStream_t stream) {
    Params p;
    p.x = (const float*)d_in[0];
    int k = 1;
    for (int l = 0; l < 11; ++l) {
        p.W[l] = (const float*)d_in[k++];
        p.b[l] = (const float*)d_in[k++];
        if (l < 10) {
            p.g[l] = (const float*)d_in[k++];
            p.bt[l] = (const float*)d_in[k++];
        }
    }
    p.out = (float*)d_out;
    p.gstats = (float*)d_ws;
    p.bar = (unsigned*)((char*)d_ws + (size_t)(10 * GSLOTS * GSTR) * sizeof(float));

    init_ws<<<dim3((10 * GSLOTS * GSTR + 255) / 256), dim3(256), 0, stream>>>(p.gstats, p.bar);
    mlp_fused<<<dim3(NBLK), dim3(NTHR), 0, stream>>>(p);
}